// Round 1
// baseline (625.292 us; speedup 1.0000x reference)
//
#include <hip/hip_runtime.h>
#include <hip/hip_bf16.h>

typedef float f32x4 __attribute__((ext_vector_type(4)));
typedef short bf16x8 __attribute__((ext_vector_type(8)));
typedef unsigned short ushort8_t __attribute__((ext_vector_type(8)));

#define L_SEQ 4096
#define DMODEL 768
#define NHEAD 12
#define HDIM 64

__device__ __forceinline__ unsigned short f2bf(float f) {
    unsigned u = __float_as_uint(f);
    unsigned r = (u + 0x7FFFu + ((u >> 16) & 1u)) >> 16;
    return (unsigned short)r;
}

// ---------------- fp32 -> bf16 conversion ----------------
__global__ __launch_bounds__(256) void cvt_f32_bf16(
    const float* __restrict__ in, unsigned short* __restrict__ out, int n)
{
    int i = (blockIdx.x * 256 + threadIdx.x) * 4;
    if (i + 3 < n) {
        float4 v = *reinterpret_cast<const float4*>(in + i);
        ushort4 o;
        o.x = f2bf(v.x); o.y = f2bf(v.y); o.z = f2bf(v.z); o.w = f2bf(v.w);
        *reinterpret_cast<ushort4*>(out + i) = o;
    }
}

// ---------------- bf16 GEMM: C[M][N] = A[M][K] * Bt[N][K]^T (fp32 out) -----
#define BM 128
#define BN 128
#define BKK 64

__global__ __launch_bounds__(256) void gemm_bf16_nt(
    const unsigned short* __restrict__ A, const unsigned short* __restrict__ Bt,
    float* __restrict__ C, int M, int N, int K)
{
    __shared__ unsigned short As[BM][BKK];
    __shared__ unsigned short Bs[BN][BKK];
    const int tid  = threadIdx.x;
    const int lane = tid & 63;
    const int wid  = tid >> 6;
    const int r = lane & 15, g = lane >> 4;
    const int wr = wid >> 1, wc = wid & 1;
    const int m0 = blockIdx.y * BM;
    const int n0 = blockIdx.x * BN;

    f32x4 acc[4][4];
    for (int i = 0; i < 4; ++i)
        for (int j = 0; j < 4; ++j)
            acc[i][j] = (f32x4){0.f, 0.f, 0.f, 0.f};

    for (int kt = 0; kt < K; kt += BKK) {
        __syncthreads();
        // stage A and Bt tiles: 128 rows x 64 cols bf16 each
        for (int p = 0; p < 4; ++p) {
            int idx = tid + p * 256;
            int row = idx >> 3;
            int ch  = (idx & 7) * 8;
            *reinterpret_cast<ushort8_t*>(&As[row][ch]) =
                *reinterpret_cast<const ushort8_t*>(&A[(size_t)(m0 + row) * K + kt + ch]);
            *reinterpret_cast<ushort8_t*>(&Bs[row][ch]) =
                *reinterpret_cast<const ushort8_t*>(&Bt[(size_t)(n0 + row) * K + kt + ch]);
        }
        __syncthreads();
        for (int k0 = 0; k0 < BKK; k0 += 32) {
            bf16x8 a[4], b[4];
            for (int i = 0; i < 4; ++i)
                a[i] = *reinterpret_cast<const bf16x8*>(&As[wr * 64 + i * 16 + r][k0 + 8 * g]);
            for (int j = 0; j < 4; ++j)
                b[j] = *reinterpret_cast<const bf16x8*>(&Bs[wc * 64 + j * 16 + r][k0 + 8 * g]);
            for (int i = 0; i < 4; ++i)
                for (int j = 0; j < 4; ++j)
                    acc[i][j] = __builtin_amdgcn_mfma_f32_16x16x32_bf16(a[i], b[j], acc[i][j], 0, 0, 0);
        }
    }
    for (int i = 0; i < 4; ++i)
        for (int j = 0; j < 4; ++j)
            for (int t = 0; t < 4; ++t) {
                int row = m0 + wr * 64 + i * 16 + 4 * g + t;
                int col = n0 + wc * 64 + j * 16 + r;
                C[(size_t)row * N + col] = acc[i][j][t];
            }
}

// ---------------- RMSnorm + RoPE + scale + layout kernel ----------------
// qkv fp32 [B*L][2304] -> Qb,Kb bf16 [BH][L][64], Vt bf16 [BH][64][L]
__global__ __launch_bounds__(256) void normrope(
    const float* __restrict__ qkv, const float* __restrict__ cosb,
    const float* __restrict__ sinb, const float* __restrict__ qw,
    const float* __restrict__ kw,
    unsigned short* __restrict__ Qb, unsigned short* __restrict__ Kb,
    unsigned short* __restrict__ Vt)
{
    __shared__ unsigned short vt[64][66];
    int blk = blockIdx.x;
    int lt = blk & 63;       // L/64 = 64 tiles
    int bh = blk >> 6;       // 0..23
    int b = bh / NHEAD, h = bh % NHEAD;
    int wid = threadIdx.x >> 6, lane = threadIdx.x & 63;
    float qwv = qw[lane], kwv = kw[lane];
    float sgn = (lane < 32) ? -1.f : 1.f;

    for (int i = 0; i < 16; ++i) {
        int ll = wid * 16 + i;
        int l = lt * 64 + ll;
        size_t rowb = ((size_t)(b * L_SEQ + l)) * (3 * DMODEL) + h * HDIM + lane;
        float qv = qkv[rowb];
        float kv = qkv[rowb + DMODEL];
        float vv = qkv[rowb + 2 * DMODEL];
        float sq = qv * qv, sk = kv * kv;
        for (int off = 32; off; off >>= 1) {
            sq += __shfl_xor(sq, off);
            sk += __shfl_xor(sk, off);
        }
        float qn = qv * rsqrtf(sq * (1.f / 64.f) + 1e-6f) * qwv;
        float kn = kv * rsqrtf(sk * (1.f / 64.f) + 1e-6f) * kwv;
        float c = cosb[l * HDIM + lane], s = sinb[l * HDIM + lane];
        float qo = __shfl_xor(qn, 32), ko = __shfl_xor(kn, 32);
        float qr = qn * c + sgn * qo * s;
        float kr = kn * c + sgn * ko * s;
        qr *= 0.125f;  // fold 1/sqrt(HD) into Q
        size_t o = ((size_t)bh * L_SEQ + l) * HDIM + lane;
        Qb[o] = f2bf(qr);
        Kb[o] = f2bf(kr);
        vt[ll][lane] = f2bf(vv);
    }
    __syncthreads();
    for (int i = 0; i < 16; ++i) {
        int d = wid * 16 + i;
        Vt[((size_t)bh * HDIM + d) * L_SEQ + lt * 64 + lane] = vt[lane][d];
    }
}

// ---------------- flash attention ----------------
// Q,K bf16 [BH][L][64] (Q pre-scaled), Vt bf16 [BH][64][L] -> aob bf16 [B][L][768]
__global__ __launch_bounds__(256) void flashattn(
    const unsigned short* __restrict__ Qb, const unsigned short* __restrict__ Kb,
    const unsigned short* __restrict__ Vt, unsigned short* __restrict__ aob)
{
    __shared__ unsigned short Ks[32][64];
    __shared__ unsigned short Vs[64][32];
    __shared__ unsigned short P[4][16][32];

    const int bh = blockIdx.y;
    const int b = bh / NHEAD, h = bh % NHEAD;
    const int tid = threadIdx.x;
    const int wid = tid >> 6, lane = tid & 63;
    const int r = lane & 15, g = lane >> 4;
    const int q0 = blockIdx.x * 64 + wid * 16;

    const unsigned short* Qp = Qb + ((size_t)bh * L_SEQ + q0 + r) * HDIM;
    const bf16x8 qf0 = *reinterpret_cast<const bf16x8*>(&Qp[8 * g]);
    const bf16x8 qf1 = *reinterpret_cast<const bf16x8*>(&Qp[32 + 8 * g]);

    const unsigned short* Kbase = Kb + (size_t)bh * L_SEQ * HDIM;
    const unsigned short* Vbase = Vt + (size_t)bh * HDIM * L_SEQ;

    f32x4 o[4];
    for (int j = 0; j < 4; ++j) o[j] = (f32x4){0.f, 0.f, 0.f, 0.f};
    float m[4], lsum[4];
    for (int t = 0; t < 4; ++t) { m[t] = -1e30f; lsum[t] = 0.f; }

    for (int kb = 0; kb < L_SEQ; kb += 32) {
        __syncthreads();
        // stage K tile (32 x 64) and Vt slice (64 x 32)
        {
            int row = tid >> 3, ch = (tid & 7) * 8;  // 32 rows x 8 chunks
            *reinterpret_cast<ushort8_t*>(&Ks[row][ch]) =
                *reinterpret_cast<const ushort8_t*>(&Kbase[(size_t)(kb + row) * HDIM + ch]);
            int vrow = tid >> 2, vch = (tid & 3) * 8;  // 64 rows x 4 chunks
            *reinterpret_cast<ushort8_t*>(&Vs[vrow][vch]) =
                *reinterpret_cast<const ushort8_t*>(&Vbase[(size_t)vrow * L_SEQ + kb + vch]);
        }
        __syncthreads();

        f32x4 s0 = (f32x4){0.f, 0.f, 0.f, 0.f};
        f32x4 s1 = (f32x4){0.f, 0.f, 0.f, 0.f};
        {
            bf16x8 kf0 = *reinterpret_cast<const bf16x8*>(&Ks[r][8 * g]);
            bf16x8 kf1 = *reinterpret_cast<const bf16x8*>(&Ks[r][32 + 8 * g]);
            s0 = __builtin_amdgcn_mfma_f32_16x16x32_bf16(qf0, kf0, s0, 0, 0, 0);
            s0 = __builtin_amdgcn_mfma_f32_16x16x32_bf16(qf1, kf1, s0, 0, 0, 0);
            bf16x8 kf2 = *reinterpret_cast<const bf16x8*>(&Ks[16 + r][8 * g]);
            bf16x8 kf3 = *reinterpret_cast<const bf16x8*>(&Ks[16 + r][32 + 8 * g]);
            s1 = __builtin_amdgcn_mfma_f32_16x16x32_bf16(qf0, kf2, s1, 0, 0, 0);
            s1 = __builtin_amdgcn_mfma_f32_16x16x32_bf16(qf1, kf3, s1, 0, 0, 0);
        }
        // online softmax (rows live at row=4g+t, col=r)
        float mx[4], p0[4], p1[4], al[4], rs[4];
        for (int t = 0; t < 4; ++t) mx[t] = fmaxf(s0[t], s1[t]);
        for (int off = 1; off < 16; off <<= 1)
            for (int t = 0; t < 4; ++t) mx[t] = fmaxf(mx[t], __shfl_xor(mx[t], off));
        for (int t = 0; t < 4; ++t) {
            float mn = fmaxf(m[t], mx[t]);
            al[t] = __expf(m[t] - mn);
            m[t] = mn;
            p0[t] = __expf(s0[t] - mn);
            p1[t] = __expf(s1[t] - mn);
            rs[t] = p0[t] + p1[t];
        }
        for (int off = 1; off < 16; off <<= 1)
            for (int t = 0; t < 4; ++t) rs[t] += __shfl_xor(rs[t], off);
        for (int t = 0; t < 4; ++t) lsum[t] = lsum[t] * al[t] + rs[t];
        for (int j = 0; j < 4; ++j)
            for (int t = 0; t < 4; ++t) o[j][t] *= al[t];
        // P: C/D layout -> A layout via per-wave LDS
        for (int t = 0; t < 4; ++t) {
            P[wid][4 * g + t][r] = f2bf(p0[t]);
            P[wid][4 * g + t][16 + r] = f2bf(p1[t]);
        }
        bf16x8 pa = *reinterpret_cast<const bf16x8*>(&P[wid][r][8 * g]);
        for (int j = 0; j < 4; ++j) {
            bf16x8 vf = *reinterpret_cast<const bf16x8*>(&Vs[j * 16 + r][8 * g]);
            o[j] = __builtin_amdgcn_mfma_f32_16x16x32_bf16(pa, vf, o[j], 0, 0, 0);
        }
    }

    for (int j = 0; j < 4; ++j)
        for (int t = 0; t < 4; ++t) {
            int row = q0 + 4 * g + t;
            float inv = 1.f / lsum[t];
            aob[((size_t)(b * L_SEQ + row)) * DMODEL + h * HDIM + j * 16 + r] =
                f2bf(o[j][t] * inv);
        }
}

// ---------------- launch ----------------
extern "C" void kernel_launch(void* const* d_in, const int* in_sizes, int n_in,
                              void* d_out, int out_size, void* d_ws, size_t ws_size,
                              hipStream_t stream) {
    const float* x        = (const float*)d_in[0];
    const float* rope_cos = (const float*)d_in[1];
    const float* rope_sin = (const float*)d_in[2];
    const float* Wqkv     = (const float*)d_in[3];
    const float* Wout     = (const float*)d_in[4];
    const float* q_norm_w = (const float*)d_in[5];
    const float* k_norm_w = (const float*)d_in[6];
    float* out = (float*)d_out;

    const int BL = 2 * L_SEQ;              // 8192
    const int nx    = BL * DMODEL;         // 6291456
    const int nwqkv = 3 * DMODEL * DMODEL; // 1769472
    const int nwout = DMODEL * DMODEL;     // 589824
    const int nqkv  = BL * 3 * DMODEL;     // 18874368

    char* w = (char*)d_ws;
    unsigned short* xb    = (unsigned short*)w; w += (size_t)nx * 2;
    unsigned short* wqkvb = (unsigned short*)w; w += (size_t)nwqkv * 2;
    unsigned short* woutb = (unsigned short*)w; w += (size_t)nwout * 2;
    unsigned short* Qb    = (unsigned short*)w; w += (size_t)nx * 2;
    unsigned short* Kb    = (unsigned short*)w; w += (size_t)nx * 2;
    unsigned short* Vtb   = (unsigned short*)w; w += (size_t)nx * 2;
    float* qkv = (float*)w; w += (size_t)nqkv * 4;
    unsigned short* aob = (unsigned short*)qkv;  // reuse: qkv dead after normrope

    // 1. convert inputs to bf16
    cvt_f32_bf16<<<nx / 1024, 256, 0, stream>>>(x, xb, nx);
    cvt_f32_bf16<<<nwqkv / 1024, 256, 0, stream>>>(Wqkv, wqkvb, nwqkv);
    cvt_f32_bf16<<<nwout / 1024, 256, 0, stream>>>(Wout, woutb, nwout);

    // 2. QKV GEMM: [8192][768] x [2304][768]^T -> fp32 [8192][2304]
    {
        dim3 grid(3 * DMODEL / BN, BL / BM);
        gemm_bf16_nt<<<grid, 256, 0, stream>>>(xb, wqkvb, qkv, BL, 3 * DMODEL, DMODEL);
    }

    // 3. RMSnorm + RoPE + scale + V transpose
    normrope<<<24 * 64, 256, 0, stream>>>(qkv, rope_cos, rope_sin, q_norm_w, k_norm_w,
                                          Qb, Kb, Vtb);

    // 4. flash attention -> aob bf16 [B][L][768]   (aliases qkv region, qkv is dead)
    {
        dim3 grid(L_SEQ / 64, 24);
        flashattn<<<grid, 256, 0, stream>>>(Qb, Kb, Vtb, aob);
    }

    // 5. out GEMM: [8192][768] x [768][768]^T -> fp32 d_out
    {
        dim3 grid(DMODEL / BN, BL / BM);
        gemm_bf16_nt<<<grid, 256, 0, stream>>>(aob, woutb, out, BL, DMODEL, DMODEL);
    }
}

// Round 3
// 345.710 us; speedup vs baseline: 1.8087x; 1.8087x over previous
//
#include <hip/hip_runtime.h>
#include <hip/hip_bf16.h>

typedef float f32x4 __attribute__((ext_vector_type(4)));
typedef short bf16x8 __attribute__((ext_vector_type(8)));
typedef unsigned short ushort8_t __attribute__((ext_vector_type(8)));

#define L_SEQ 4096
#define DMODEL 768
#define NHEAD 12
#define HDIM 64

__device__ __forceinline__ unsigned short f2bf(float f) {
    unsigned u = __float_as_uint(f);
    unsigned r = (u + 0x7FFFu + ((u >> 16) & 1u)) >> 16;
    return (unsigned short)r;
}

__device__ __forceinline__ unsigned pack2bf(float a, float b) {
    return (unsigned)f2bf(a) | ((unsigned)f2bf(b) << 16);
}

// ---------------- fp32 -> bf16 conversion ----------------
__global__ __launch_bounds__(256) void cvt_f32_bf16(
    const float* __restrict__ in, unsigned short* __restrict__ out, int n)
{
    int i = (blockIdx.x * 256 + threadIdx.x) * 4;
    if (i + 3 < n) {
        float4 v = *reinterpret_cast<const float4*>(in + i);
        ushort4 o;
        o.x = f2bf(v.x); o.y = f2bf(v.y); o.z = f2bf(v.z); o.w = f2bf(v.w);
        *reinterpret_cast<ushort4*>(out + i) = o;
    }
}

// ---------------- bf16 GEMM: C[M][N] = A[M][K] * Bt[N][K]^T (fp32 out) -----
#define BM 128
#define BN 128
#define BKK 64

__global__ __launch_bounds__(256) void gemm_bf16_nt(
    const unsigned short* __restrict__ A, const unsigned short* __restrict__ Bt,
    float* __restrict__ C, int M, int N, int K)
{
    __shared__ unsigned short As[BM][BKK];
    __shared__ unsigned short Bs[BN][BKK];
    const int tid  = threadIdx.x;
    const int lane = tid & 63;
    const int wid  = tid >> 6;
    const int r = lane & 15, g = lane >> 4;
    const int wr = wid >> 1, wc = wid & 1;
    const int m0 = blockIdx.y * BM;
    const int n0 = blockIdx.x * BN;

    f32x4 acc[4][4];
    for (int i = 0; i < 4; ++i)
        for (int j = 0; j < 4; ++j)
            acc[i][j] = (f32x4){0.f, 0.f, 0.f, 0.f};

    for (int kt = 0; kt < K; kt += BKK) {
        __syncthreads();
        for (int p = 0; p < 4; ++p) {
            int idx = tid + p * 256;
            int row = idx >> 3;
            int ch  = (idx & 7) * 8;
            *reinterpret_cast<ushort8_t*>(&As[row][ch]) =
                *reinterpret_cast<const ushort8_t*>(&A[(size_t)(m0 + row) * K + kt + ch]);
            *reinterpret_cast<ushort8_t*>(&Bs[row][ch]) =
                *reinterpret_cast<const ushort8_t*>(&Bt[(size_t)(n0 + row) * K + kt + ch]);
        }
        __syncthreads();
        for (int k0 = 0; k0 < BKK; k0 += 32) {
            bf16x8 a[4], b[4];
            for (int i = 0; i < 4; ++i)
                a[i] = *reinterpret_cast<const bf16x8*>(&As[wr * 64 + i * 16 + r][k0 + 8 * g]);
            for (int j = 0; j < 4; ++j)
                b[j] = *reinterpret_cast<const bf16x8*>(&Bs[wc * 64 + j * 16 + r][k0 + 8 * g]);
            for (int i = 0; i < 4; ++i)
                for (int j = 0; j < 4; ++j)
                    acc[i][j] = __builtin_amdgcn_mfma_f32_16x16x32_bf16(a[i], b[j], acc[i][j], 0, 0, 0);
        }
    }
    for (int i = 0; i < 4; ++i)
        for (int j = 0; j < 4; ++j)
            for (int t = 0; t < 4; ++t) {
                int row = m0 + wr * 64 + i * 16 + 4 * g + t;
                int col = n0 + wc * 64 + j * 16 + r;
                C[(size_t)row * N + col] = acc[i][j][t];
            }
}

// ---------------- RMSnorm + RoPE + scale + layout kernel ----------------
__global__ __launch_bounds__(256) void normrope(
    const float* __restrict__ qkv, const float* __restrict__ cosb,
    const float* __restrict__ sinb, const float* __restrict__ qw,
    const float* __restrict__ kw,
    unsigned short* __restrict__ Qb, unsigned short* __restrict__ Kb,
    unsigned short* __restrict__ Vt)
{
    __shared__ unsigned short vt[64][66];
    int blk = blockIdx.x;
    int lt = blk & 63;
    int bh = blk >> 6;
    int b = bh / NHEAD, h = bh % NHEAD;
    int wid = threadIdx.x >> 6, lane = threadIdx.x & 63;
    float qwv = qw[lane], kwv = kw[lane];
    float sgn = (lane < 32) ? -1.f : 1.f;

    for (int i = 0; i < 16; ++i) {
        int ll = wid * 16 + i;
        int l = lt * 64 + ll;
        size_t rowb = ((size_t)(b * L_SEQ + l)) * (3 * DMODEL) + h * HDIM + lane;
        float qv = qkv[rowb];
        float kv = qkv[rowb + DMODEL];
        float vv = qkv[rowb + 2 * DMODEL];
        float sq = qv * qv, sk = kv * kv;
        for (int off = 32; off; off >>= 1) {
            sq += __shfl_xor(sq, off);
            sk += __shfl_xor(sk, off);
        }
        float qn = qv * rsqrtf(sq * (1.f / 64.f) + 1e-6f) * qwv;
        float kn = kv * rsqrtf(sk * (1.f / 64.f) + 1e-6f) * kwv;
        float c = cosb[l * HDIM + lane], s = sinb[l * HDIM + lane];
        float qo = __shfl_xor(qn, 32), ko = __shfl_xor(kn, 32);
        float qr = qn * c + sgn * qo * s;
        float kr = kn * c + sgn * ko * s;
        qr *= 0.125f;
        size_t o = ((size_t)bh * L_SEQ + l) * HDIM + lane;
        Qb[o] = f2bf(qr);
        Kb[o] = f2bf(kr);
        vt[ll][lane] = f2bf(vv);
    }
    __syncthreads();
    for (int i = 0; i < 16; ++i) {
        int d = wid * 16 + i;
        Vt[((size_t)bh * HDIM + d) * L_SEQ + lt * 64 + lane] = vt[lane][d];
    }
}

// ---------------- flash attention (swapped-QK, swizzled LDS) ----------------
// Q,K bf16 [BH][L][64] (Q pre-scaled), Vt bf16 [BH][64][L] -> aob bf16 [B][L][768]
// Per block: 4 waves x 32 q-rows = 128 q. KBLK = 64.
__global__ __launch_bounds__(256) void flashattn(
    const unsigned short* __restrict__ Qb, const unsigned short* __restrict__ Kb,
    const unsigned short* __restrict__ Vt, unsigned short* __restrict__ aob)
{
    __shared__ unsigned short Ks[64 * 64];   // [k=64][d=64], swizzled
    __shared__ unsigned short Vs[64 * 64];   // [d=64][k=64], swizzled
    __shared__ unsigned short Ps[4][32 * 64]; // per-wave [q=32][k=64], swizzled

    const int bh = blockIdx.y;
    const int b = bh / NHEAD, h = bh % NHEAD;
    const int tid = threadIdx.x;
    const int wid = tid >> 6, lane = tid & 63;
    const int r = lane & 15, g = lane >> 4;
    const int q0 = blockIdx.x * 128 + wid * 32;
    const int rsw = (r & 7) << 4;

    // Q frags: lane holds Q[q0 + i*16 + r][c*32 + 8g .. +7]
    bf16x8 qf[2][2];
    for (int i = 0; i < 2; ++i) {
        const unsigned short* Qp = Qb + ((size_t)bh * L_SEQ + q0 + i * 16 + r) * HDIM + 8 * g;
        qf[i][0] = *reinterpret_cast<const bf16x8*>(Qp);
        qf[i][1] = *reinterpret_cast<const bf16x8*>(Qp + 32);
    }

    const unsigned short* Kbase = Kb + (size_t)bh * L_SEQ * HDIM;
    const unsigned short* Vbase = Vt + (size_t)bh * HDIM * L_SEQ;

    char* KsB = (char*)Ks;
    char* VsB = (char*)Vs;
    char* PsB = (char*)Ps[wid];

    f32x4 o[2][4];
    for (int i = 0; i < 2; ++i)
        for (int j = 0; j < 4; ++j) o[i][j] = (f32x4){0.f, 0.f, 0.f, 0.f};
    float m_[2] = {-1e30f, -1e30f};
    float l_[2] = {0.f, 0.f};

    for (int kb = 0; kb < L_SEQ; kb += 64) {
        __syncthreads();
        // stage K (64 k-rows x 64 d) and V^T (64 d-rows x 64 k), XOR-swizzled
        for (int p = 0; p < 2; ++p) {
            int idx = tid + p * 256;
            int row = idx >> 3;
            int cb = (idx & 7) * 16;
            int dst = row * 128 + (cb ^ ((row & 7) << 4));
            *reinterpret_cast<ushort8_t*>(KsB + dst) =
                *reinterpret_cast<const ushort8_t*>(Kbase + (size_t)(kb + row) * HDIM + (idx & 7) * 8);
            *reinterpret_cast<ushort8_t*>(VsB + dst) =
                *reinterpret_cast<const ushort8_t*>(Vbase + (size_t)row * L_SEQ + kb + (idx & 7) * 8);
        }
        __syncthreads();

        // QK^T swapped: s[i][kt] = K-tile(kt) x Q(i) -> S[q=r][k=kt*16+4g+t]
        f32x4 s[2][4];
        for (int i = 0; i < 2; ++i)
            for (int kt = 0; kt < 4; ++kt) s[i][kt] = (f32x4){0.f, 0.f, 0.f, 0.f};
        for (int kt = 0; kt < 4; ++kt) {
            bf16x8 kf0 = *reinterpret_cast<const bf16x8*>(KsB + (kt * 16 + r) * 128 + ((16 * g) ^ rsw));
            bf16x8 kf1 = *reinterpret_cast<const bf16x8*>(KsB + (kt * 16 + r) * 128 + ((64 + 16 * g) ^ rsw));
            for (int i = 0; i < 2; ++i) {
                s[i][kt] = __builtin_amdgcn_mfma_f32_16x16x32_bf16(kf0, qf[i][0], s[i][kt], 0, 0, 0);
                s[i][kt] = __builtin_amdgcn_mfma_f32_16x16x32_bf16(kf1, qf[i][1], s[i][kt], 0, 0, 0);
            }
        }

        // online softmax: row q=r is lane-local over 16 regs, x4 over g
        for (int i = 0; i < 2; ++i) {
            float mx = fmaxf(fmaxf(fmaxf(s[i][0][0], s[i][0][1]), fmaxf(s[i][0][2], s[i][0][3])),
                     fmaxf(fmaxf(fmaxf(s[i][1][0], s[i][1][1]), fmaxf(s[i][1][2], s[i][1][3])),
                     fmaxf(fmaxf(fmaxf(s[i][2][0], s[i][2][1]), fmaxf(s[i][2][2], s[i][2][3])),
                           fmaxf(fmaxf(s[i][3][0], s[i][3][1]), fmaxf(s[i][3][2], s[i][3][3])))));
            mx = fmaxf(mx, __shfl_xor(mx, 16));
            mx = fmaxf(mx, __shfl_xor(mx, 32));
            float mn = fmaxf(m_[i], mx);
            float sc = __expf(m_[i] - mn);
            m_[i] = mn;
            float rs = 0.f;
            for (int kt = 0; kt < 4; ++kt)
                for (int t = 0; t < 4; ++t) {
                    float p = __expf(s[i][kt][t] - mn);
                    s[i][kt][t] = p;
                    rs += p;
                }
            rs += __shfl_xor(rs, 16);
            rs += __shfl_xor(rs, 32);
            l_[i] = l_[i] * sc + rs;

            // write P^T->P into per-wave LDS in bf16 (8B per kt), swizzled
            for (int kt = 0; kt < 4; ++kt) {
                unsigned lo = pack2bf(s[i][kt][0], s[i][kt][1]);
                unsigned hi = pack2bf(s[i][kt][2], s[i][kt][3]);
                int dst = (i * 16 + r) * 128 + ((kt * 32 + 8 * g) ^ rsw);
                uint2 w2; w2.x = lo; w2.y = hi;
                *reinterpret_cast<uint2*>(PsB + dst) = w2;
            }

            // rescale O: O rows are q = i*16 + 4g+t; sc lives at lane r = 4g+t
            float a0 = __shfl(sc, 4 * g + 0);
            float a1 = __shfl(sc, 4 * g + 1);
            float a2 = __shfl(sc, 4 * g + 2);
            float a3 = __shfl(sc, 4 * g + 3);
            for (int j = 0; j < 4; ++j) {
                o[i][j][0] *= a0; o[i][j][1] *= a1;
                o[i][j][2] *= a2; o[i][j][3] *= a3;
            }
        }

        // PV: read P A-frags (per-wave LDS), V^T B-frags (shared LDS)
        bf16x8 pa[2][2];
        for (int i = 0; i < 2; ++i) {
            pa[i][0] = *reinterpret_cast<const bf16x8*>(PsB + (i * 16 + r) * 128 + ((16 * g) ^ rsw));
            pa[i][1] = *reinterpret_cast<const bf16x8*>(PsB + (i * 16 + r) * 128 + ((64 + 16 * g) ^ rsw));
        }
        for (int j = 0; j < 4; ++j) {
            bf16x8 vf0 = *reinterpret_cast<const bf16x8*>(VsB + (j * 16 + r) * 128 + ((16 * g) ^ rsw));
            bf16x8 vf1 = *reinterpret_cast<const bf16x8*>(VsB + (j * 16 + r) * 128 + ((64 + 16 * g) ^ rsw));
            for (int i = 0; i < 2; ++i) {
                o[i][j] = __builtin_amdgcn_mfma_f32_16x16x32_bf16(pa[i][0], vf0, o[i][j], 0, 0, 0);
                o[i][j] = __builtin_amdgcn_mfma_f32_16x16x32_bf16(pa[i][1], vf1, o[i][j], 0, 0, 0);
            }
        }
    }

    // epilogue: O rows q = i*16+4g+t, col d = j*16+r; 1/l lives at lane r=q
    for (int i = 0; i < 2; ++i) {
        float inv = 1.f / l_[i];
        float i0 = __shfl(inv, 4 * g + 0);
        float i1 = __shfl(inv, 4 * g + 1);
        float i2 = __shfl(inv, 4 * g + 2);
        float i3 = __shfl(inv, 4 * g + 3);
        for (int j = 0; j < 4; ++j) {
            size_t base = ((size_t)(b * L_SEQ + q0 + i * 16 + 4 * g)) * DMODEL + h * HDIM + j * 16 + r;
            aob[base] = f2bf(o[i][j][0] * i0);
            aob[base + DMODEL] = f2bf(o[i][j][1] * i1);
            aob[base + 2 * DMODEL] = f2bf(o[i][j][2] * i2);
            aob[base + 3 * DMODEL] = f2bf(o[i][j][3] * i3);
        }
    }
}

// ---------------- launch ----------------
extern "C" void kernel_launch(void* const* d_in, const int* in_sizes, int n_in,
                              void* d_out, int out_size, void* d_ws, size_t ws_size,
                              hipStream_t stream) {
    const float* x        = (const float*)d_in[0];
    const float* rope_cos = (const float*)d_in[1];
    const float* rope_sin = (const float*)d_in[2];
    const float* Wqkv     = (const float*)d_in[3];
    const float* Wout     = (const float*)d_in[4];
    const float* q_norm_w = (const float*)d_in[5];
    const float* k_norm_w = (const float*)d_in[6];
    float* out = (float*)d_out;

    const int BL = 2 * L_SEQ;
    const int nx    = BL * DMODEL;
    const int nwqkv = 3 * DMODEL * DMODEL;
    const int nwout = DMODEL * DMODEL;
    const int nqkv  = BL * 3 * DMODEL;

    char* w = (char*)d_ws;
    unsigned short* xb    = (unsigned short*)w; w += (size_t)nx * 2;
    unsigned short* wqkvb = (unsigned short*)w; w += (size_t)nwqkv * 2;
    unsigned short* woutb = (unsigned short*)w; w += (size_t)nwout * 2;
    unsigned short* Qb    = (unsigned short*)w; w += (size_t)nx * 2;
    unsigned short* Kb    = (unsigned short*)w; w += (size_t)nx * 2;
    unsigned short* Vtb   = (unsigned short*)w; w += (size_t)nx * 2;
    float* qkv = (float*)w; w += (size_t)nqkv * 4;
    unsigned short* aob = (unsigned short*)qkv;

    cvt_f32_bf16<<<nx / 1024, 256, 0, stream>>>(x, xb, nx);
    cvt_f32_bf16<<<nwqkv / 1024, 256, 0, stream>>>(Wqkv, wqkvb, nwqkv);
    cvt_f32_bf16<<<nwout / 1024, 256, 0, stream>>>(Wout, woutb, nwout);

    {
        dim3 grid(3 * DMODEL / BN, BL / BM);
        gemm_bf16_nt<<<grid, 256, 0, stream>>>(xb, wqkvb, qkv, BL, 3 * DMODEL, DMODEL);
    }

    normrope<<<24 * 64, 256, 0, stream>>>(qkv, rope_cos, rope_sin, q_norm_w, k_norm_w,
                                          Qb, Kb, Vtb);

    {
        dim3 grid(L_SEQ / 128, 24);
        flashattn<<<grid, 256, 0, stream>>>(Qb, Kb, Vtb, aob);
    }

    {
        dim3 grid(DMODEL / BN, BL / BM);
        gemm_bf16_nt<<<grid, 256, 0, stream>>>(aob, woutb, out, BL, DMODEL, DMODEL);
    }
}

// Round 4
// 322.534 us; speedup vs baseline: 1.9387x; 1.0719x over previous
//
#include <hip/hip_runtime.h>
#include <hip/hip_bf16.h>

typedef float f32x4 __attribute__((ext_vector_type(4)));
typedef short bf16x8 __attribute__((ext_vector_type(8)));
typedef unsigned short ushort8_t __attribute__((ext_vector_type(8)));

#define L_SEQ 4096
#define DMODEL 768
#define NHEAD 12
#define HDIM 64

__device__ __forceinline__ unsigned short f2bf(float f) {
    __hip_bfloat16 h = __float2bfloat16(f);
    return *reinterpret_cast<unsigned short*>(&h);
}

__device__ __forceinline__ unsigned pack2bf(float a, float b) {
    return (unsigned)f2bf(a) | ((unsigned)f2bf(b) << 16);
}

__device__ __forceinline__ void gload16(const void* g, void* l) {
    __builtin_amdgcn_global_load_lds(
        (const __attribute__((address_space(1))) unsigned int*)g,
        (__attribute__((address_space(3))) unsigned int*)l, 16, 0, 0);
}

// ---------------- fp32 -> bf16 conversion ----------------
__global__ __launch_bounds__(256) void cvt_f32_bf16(
    const float* __restrict__ in, unsigned short* __restrict__ out, int n)
{
    int i = (blockIdx.x * 256 + threadIdx.x) * 4;
    if (i + 3 < n) {
        float4 v = *reinterpret_cast<const float4*>(in + i);
        ushort4 o;
        o.x = f2bf(v.x); o.y = f2bf(v.y); o.z = f2bf(v.z); o.w = f2bf(v.w);
        *reinterpret_cast<ushort4*>(out + i) = o;
    }
}

// ---------------- bf16 GEMM: C[M][N] = A[M][K] * Bt[N][K]^T (fp32 out) -----
#define BM 128
#define BN 128
#define BKK 64

__global__ __launch_bounds__(256) void gemm_bf16_nt(
    const unsigned short* __restrict__ A, const unsigned short* __restrict__ Bt,
    float* __restrict__ C, int M, int N, int K)
{
    __shared__ unsigned short As[BM][BKK];
    __shared__ unsigned short Bs[BN][BKK];
    const int tid  = threadIdx.x;
    const int lane = tid & 63;
    const int wid  = tid >> 6;
    const int r = lane & 15, g = lane >> 4;
    const int wr = wid >> 1, wc = wid & 1;
    const int m0 = blockIdx.y * BM;
    const int n0 = blockIdx.x * BN;

    f32x4 acc[4][4];
    for (int i = 0; i < 4; ++i)
        for (int j = 0; j < 4; ++j)
            acc[i][j] = (f32x4){0.f, 0.f, 0.f, 0.f};

    for (int kt = 0; kt < K; kt += BKK) {
        __syncthreads();
        // stage via global_load_lds width=16: LDS dest linear in staging index
        for (int p = 0; p < 4; ++p) {
            int idx = wid * 64 + p * 256 + lane;
            int row = idx >> 3;
            int ch  = (idx & 7) * 8;
            gload16(&A[(size_t)(m0 + row) * K + kt + ch],
                    (char*)As + (size_t)(wid * 64 + p * 256) * 16);
            gload16(&Bt[(size_t)(n0 + row) * K + kt + ch],
                    (char*)Bs + (size_t)(wid * 64 + p * 256) * 16);
        }
        __syncthreads();
        for (int k0 = 0; k0 < BKK; k0 += 32) {
            bf16x8 a[4], b[4];
            for (int i = 0; i < 4; ++i)
                a[i] = *reinterpret_cast<const bf16x8*>(&As[wr * 64 + i * 16 + r][k0 + 8 * g]);
            for (int j = 0; j < 4; ++j)
                b[j] = *reinterpret_cast<const bf16x8*>(&Bs[wc * 64 + j * 16 + r][k0 + 8 * g]);
            for (int i = 0; i < 4; ++i)
                for (int j = 0; j < 4; ++j)
                    acc[i][j] = __builtin_amdgcn_mfma_f32_16x16x32_bf16(a[i], b[j], acc[i][j], 0, 0, 0);
        }
    }
    for (int i = 0; i < 4; ++i)
        for (int j = 0; j < 4; ++j)
            for (int t = 0; t < 4; ++t) {
                int row = m0 + wr * 64 + i * 16 + 4 * g + t;
                int col = n0 + wc * 64 + j * 16 + r;
                C[(size_t)row * N + col] = acc[i][j][t];
            }
}

// ---------------- RMSnorm + RoPE + scale + layout kernel ----------------
__global__ __launch_bounds__(256) void normrope(
    const float* __restrict__ qkv, const float* __restrict__ cosb,
    const float* __restrict__ sinb, const float* __restrict__ qw,
    const float* __restrict__ kw,
    unsigned short* __restrict__ Qb, unsigned short* __restrict__ Kb,
    unsigned short* __restrict__ Vt)
{
    __shared__ unsigned short vt[64][66];
    int blk = blockIdx.x;
    int lt = blk & 63;
    int bh = blk >> 6;
    int b = bh / NHEAD, h = bh % NHEAD;
    int wid = threadIdx.x >> 6, lane = threadIdx.x & 63;
    float qwv = qw[lane], kwv = kw[lane];
    float sgn = (lane < 32) ? -1.f : 1.f;

    for (int i = 0; i < 16; ++i) {
        int ll = wid * 16 + i;
        int l = lt * 64 + ll;
        size_t rowb = ((size_t)(b * L_SEQ + l)) * (3 * DMODEL) + h * HDIM + lane;
        float qv = qkv[rowb];
        float kv = qkv[rowb + DMODEL];
        float vv = qkv[rowb + 2 * DMODEL];
        float sq = qv * qv, sk = kv * kv;
        for (int off = 32; off; off >>= 1) {
            sq += __shfl_xor(sq, off);
            sk += __shfl_xor(sk, off);
        }
        float qn = qv * rsqrtf(sq * (1.f / 64.f) + 1e-6f) * qwv;
        float kn = kv * rsqrtf(sk * (1.f / 64.f) + 1e-6f) * kwv;
        float c = cosb[l * HDIM + lane], s = sinb[l * HDIM + lane];
        float qo = __shfl_xor(qn, 32), ko = __shfl_xor(kn, 32);
        float qr = qn * c + sgn * qo * s;
        float kr = kn * c + sgn * ko * s;
        qr *= 0.125f * 1.44269504f;   // fold 1/sqrt(HD) AND log2(e) into Q (exp2 softmax)
        size_t o = ((size_t)bh * L_SEQ + l) * HDIM + lane;
        Qb[o] = f2bf(qr);
        Kb[o] = f2bf(kr);
        vt[ll][lane] = f2bf(vv);
    }
    __syncthreads();
    for (int i = 0; i < 16; ++i) {
        int d = wid * 16 + i;
        Vt[((size_t)bh * HDIM + d) * L_SEQ + lt * 64 + lane] = vt[lane][d];
    }
}

// ---------------- flash attention (swapped-QK, swizzled LDS, dbuf) --------
// Q,K bf16 [BH][L][64] (Q pre-scaled incl log2e), Vt bf16 [BH][64][L]
// Per block: 4 waves x 32 q-rows = 128 q. KBLK = 64. Double-buffered K/V.
__global__ __launch_bounds__(256, 3) void flashattn(
    const unsigned short* __restrict__ Qb, const unsigned short* __restrict__ Kb,
    const unsigned short* __restrict__ Vt, unsigned short* __restrict__ aob)
{
    __shared__ unsigned short Ks[2][64 * 64];   // [k=64][d=64], swizzled
    __shared__ unsigned short Vs[2][64 * 64];   // [d=64][k=64], swizzled
    __shared__ unsigned short Ps[4][32 * 64];   // per-wave [q=32][k=64], swizzled

    const int bh = blockIdx.y;
    const int b = bh / NHEAD, h = bh % NHEAD;
    const int tid = threadIdx.x;
    const int wid = tid >> 6, lane = tid & 63;
    const int r = lane & 15, g = lane >> 4;
    const int q0 = blockIdx.x * 128 + wid * 32;
    const int rsw = (r & 7) << 4;

    // Q frags: lane holds Q[q0 + i*16 + r][c*32 + 8g .. +7]
    bf16x8 qf[2][2];
    for (int i = 0; i < 2; ++i) {
        const unsigned short* Qp = Qb + ((size_t)bh * L_SEQ + q0 + i * 16 + r) * HDIM + 8 * g;
        qf[i][0] = *reinterpret_cast<const bf16x8*>(Qp);
        qf[i][1] = *reinterpret_cast<const bf16x8*>(Qp + 32);
    }

    const unsigned short* Kbase = Kb + (size_t)bh * L_SEQ * HDIM;
    const unsigned short* Vbase = Vt + (size_t)bh * HDIM * L_SEQ;
    char* PsB = (char*)Ps[wid];

    f32x4 o[2][4];
    for (int i = 0; i < 2; ++i)
        for (int j = 0; j < 4; ++j) o[i][j] = (f32x4){0.f, 0.f, 0.f, 0.f};
    float m_[2] = {-1e30f, -1e30f};
    float l_[2] = {0.f, 0.f};

    // stage: global_load_lds with PRE-SWIZZLED global source, linear LDS dest
    auto stage = [&](int buf, int kb) {
        for (int p = 0; p < 2; ++p) {
            int idx = wid * 64 + p * 256 + lane;
            int row = idx >> 3;
            int colb = ((idx & 7) * 16) ^ ((row & 7) << 4);   // byte offset in 128B row
            gload16(Kbase + (size_t)(kb + row) * HDIM + (colb >> 1),
                    (char*)Ks[buf] + (size_t)(wid * 64 + p * 256) * 16);
            gload16(Vbase + (size_t)row * L_SEQ + kb + (colb >> 1),
                    (char*)Vs[buf] + (size_t)(wid * 64 + p * 256) * 16);
        }
    };

    stage(0, 0);
    __syncthreads();        // drains vmcnt -> buffer 0 ready
    int cur = 0;

    for (int kb = 0; kb < L_SEQ; kb += 64) {
        // prefetch next tile into the other buffer (latency hides under compute)
        if (kb + 64 < L_SEQ) stage(cur ^ 1, kb + 64);
        char* KsB = (char*)Ks[cur];
        char* VsB = (char*)Vs[cur];

        // QK^T swapped: s[i][kt] = K-tile(kt) x Q(i) -> S[q=r][k=kt*16+4g+t]
        f32x4 s[2][4];
        for (int i = 0; i < 2; ++i)
            for (int kt = 0; kt < 4; ++kt) s[i][kt] = (f32x4){0.f, 0.f, 0.f, 0.f};
        for (int kt = 0; kt < 4; ++kt) {
            bf16x8 kf0 = *reinterpret_cast<const bf16x8*>(KsB + (kt * 16 + r) * 128 + ((16 * g) ^ rsw));
            bf16x8 kf1 = *reinterpret_cast<const bf16x8*>(KsB + (kt * 16 + r) * 128 + ((64 + 16 * g) ^ rsw));
            for (int i = 0; i < 2; ++i) {
                s[i][kt] = __builtin_amdgcn_mfma_f32_16x16x32_bf16(kf0, qf[i][0], s[i][kt], 0, 0, 0);
                s[i][kt] = __builtin_amdgcn_mfma_f32_16x16x32_bf16(kf1, qf[i][1], s[i][kt], 0, 0, 0);
            }
        }

        // online softmax in log2 domain, defer-max (THR=8)
        for (int i = 0; i < 2; ++i) {
            float mx = fmaxf(fmaxf(fmaxf(s[i][0][0], s[i][0][1]), fmaxf(s[i][0][2], s[i][0][3])),
                     fmaxf(fmaxf(fmaxf(s[i][1][0], s[i][1][1]), fmaxf(s[i][1][2], s[i][1][3])),
                     fmaxf(fmaxf(fmaxf(s[i][2][0], s[i][2][1]), fmaxf(s[i][2][2], s[i][2][3])),
                           fmaxf(fmaxf(s[i][3][0], s[i][3][1]), fmaxf(s[i][3][2], s[i][3][3])))));
            mx = fmaxf(mx, __shfl_xor(mx, 16));
            mx = fmaxf(mx, __shfl_xor(mx, 32));
            float sc = 1.f;
            if (!__all(mx <= m_[i] + 8.f)) {     // wave-uniform branch
                float mn = fmaxf(m_[i], mx);
                sc = exp2f(m_[i] - mn);
                m_[i] = mn;
                float a0 = __shfl(sc, 4 * g + 0);
                float a1 = __shfl(sc, 4 * g + 1);
                float a2 = __shfl(sc, 4 * g + 2);
                float a3 = __shfl(sc, 4 * g + 3);
                for (int j = 0; j < 4; ++j) {
                    o[i][j][0] *= a0; o[i][j][1] *= a1;
                    o[i][j][2] *= a2; o[i][j][3] *= a3;
                }
            }
            float rs = 0.f;
            for (int kt = 0; kt < 4; ++kt)
                for (int t = 0; t < 4; ++t) {
                    float p = exp2f(s[i][kt][t] - m_[i]);
                    s[i][kt][t] = p;
                    rs += p;
                }
            rs += __shfl_xor(rs, 16);
            rs += __shfl_xor(rs, 32);
            l_[i] = l_[i] * sc + rs;

            // write P (bf16, HW cvt_pk) into per-wave LDS, swizzled
            for (int kt = 0; kt < 4; ++kt) {
                unsigned lo = pack2bf(s[i][kt][0], s[i][kt][1]);
                unsigned hi = pack2bf(s[i][kt][2], s[i][kt][3]);
                int dst = (i * 16 + r) * 128 + ((kt * 32 + 8 * g) ^ rsw);
                uint2 w2; w2.x = lo; w2.y = hi;
                *reinterpret_cast<uint2*>(PsB + dst) = w2;
            }
        }

        // PV: read P A-frags (per-wave LDS), V^T B-frags (shared LDS)
        bf16x8 pa[2][2];
        for (int i = 0; i < 2; ++i) {
            pa[i][0] = *reinterpret_cast<const bf16x8*>(PsB + (i * 16 + r) * 128 + ((16 * g) ^ rsw));
            pa[i][1] = *reinterpret_cast<const bf16x8*>(PsB + (i * 16 + r) * 128 + ((64 + 16 * g) ^ rsw));
        }
        for (int j = 0; j < 4; ++j) {
            bf16x8 vf0 = *reinterpret_cast<const bf16x8*>(VsB + (j * 16 + r) * 128 + ((16 * g) ^ rsw));
            bf16x8 vf1 = *reinterpret_cast<const bf16x8*>(VsB + (j * 16 + r) * 128 + ((64 + 16 * g) ^ rsw));
            for (int i = 0; i < 2; ++i) {
                o[i][j] = __builtin_amdgcn_mfma_f32_16x16x32_bf16(pa[i][0], vf0, o[i][j], 0, 0, 0);
                o[i][j] = __builtin_amdgcn_mfma_f32_16x16x32_bf16(pa[i][1], vf1, o[i][j], 0, 0, 0);
            }
        }
        __syncthreads();   // all waves done reading cur; prefetch drained (vmcnt 0)
        cur ^= 1;
    }

    // epilogue: O rows q = i*16+4g+t, col d = j*16+r; 1/l lives at lane r=q
    for (int i = 0; i < 2; ++i) {
        float inv = 1.f / l_[i];
        float i0 = __shfl(inv, 4 * g + 0);
        float i1 = __shfl(inv, 4 * g + 1);
        float i2 = __shfl(inv, 4 * g + 2);
        float i3 = __shfl(inv, 4 * g + 3);
        for (int j = 0; j < 4; ++j) {
            size_t base = ((size_t)(b * L_SEQ + q0 + i * 16 + 4 * g)) * DMODEL + h * HDIM + j * 16 + r;
            aob[base] = f2bf(o[i][j][0] * i0);
            aob[base + DMODEL] = f2bf(o[i][j][1] * i1);
            aob[base + 2 * DMODEL] = f2bf(o[i][j][2] * i2);
            aob[base + 3 * DMODEL] = f2bf(o[i][j][3] * i3);
        }
    }
}

// ---------------- launch ----------------
extern "C" void kernel_launch(void* const* d_in, const int* in_sizes, int n_in,
                              void* d_out, int out_size, void* d_ws, size_t ws_size,
                              hipStream_t stream) {
    const float* x        = (const float*)d_in[0];
    const float* rope_cos = (const float*)d_in[1];
    const float* rope_sin = (const float*)d_in[2];
    const float* Wqkv     = (const float*)d_in[3];
    const float* Wout     = (const float*)d_in[4];
    const float* q_norm_w = (const float*)d_in[5];
    const float* k_norm_w = (const float*)d_in[6];
    float* out = (float*)d_out;

    const int BL = 2 * L_SEQ;
    const int nx    = BL * DMODEL;
    const int nwqkv = 3 * DMODEL * DMODEL;
    const int nwout = DMODEL * DMODEL;
    const int nqkv  = BL * 3 * DMODEL;

    char* w = (char*)d_ws;
    unsigned short* xb    = (unsigned short*)w; w += (size_t)nx * 2;
    unsigned short* wqkvb = (unsigned short*)w; w += (size_t)nwqkv * 2;
    unsigned short* woutb = (unsigned short*)w; w += (size_t)nwout * 2;
    unsigned short* Qb    = (unsigned short*)w; w += (size_t)nx * 2;
    unsigned short* Kb    = (unsigned short*)w; w += (size_t)nx * 2;
    unsigned short* Vtb   = (unsigned short*)w; w += (size_t)nx * 2;
    float* qkv = (float*)w; w += (size_t)nqkv * 4;
    unsigned short* aob = (unsigned short*)qkv;

    cvt_f32_bf16<<<nx / 1024, 256, 0, stream>>>(x, xb, nx);
    cvt_f32_bf16<<<nwqkv / 1024, 256, 0, stream>>>(Wqkv, wqkvb, nwqkv);
    cvt_f32_bf16<<<nwout / 1024, 256, 0, stream>>>(Wout, woutb, nwout);

    {
        dim3 grid(3 * DMODEL / BN, BL / BM);
        gemm_bf16_nt<<<grid, 256, 0, stream>>>(xb, wqkvb, qkv, BL, 3 * DMODEL, DMODEL);
    }

    normrope<<<24 * 64, 256, 0, stream>>>(qkv, rope_cos, rope_sin, q_norm_w, k_norm_w,
                                          Qb, Kb, Vtb);

    {
        dim3 grid(L_SEQ / 128, 24);
        flashattn<<<grid, 256, 0, stream>>>(Qb, Kb, Vtb, aob);
    }

    {
        dim3 grid(DMODEL / BN, BL / BM);
        gemm_bf16_nt<<<grid, 256, 0, stream>>>(aob, woutb, out, BL, DMODEL, DMODEL);
    }
}

// Round 5
// 239.323 us; speedup vs baseline: 2.6127x; 1.3477x over previous
//
#include <hip/hip_runtime.h>
#include <hip/hip_bf16.h>

typedef float f32x4 __attribute__((ext_vector_type(4)));
typedef short bf16x8 __attribute__((ext_vector_type(8)));
typedef unsigned short ushort8_t __attribute__((ext_vector_type(8)));

#define L_SEQ 4096
#define DMODEL 768
#define NHEAD 12
#define HDIM 64

__device__ __forceinline__ unsigned short f2bf(float f) {
    __hip_bfloat16 h = __float2bfloat16(f);
    return *reinterpret_cast<unsigned short*>(&h);
}

__device__ __forceinline__ float bf2f(unsigned short u) {
    return __uint_as_float((unsigned)u << 16);
}

__device__ __forceinline__ unsigned pack2bf(float a, float b) {
    return (unsigned)f2bf(a) | ((unsigned)f2bf(b) << 16);
}

__device__ __forceinline__ void gload16(const void* g, void* l) {
    __builtin_amdgcn_global_load_lds(
        (const __attribute__((address_space(1))) unsigned int*)g,
        (__attribute__((address_space(3))) unsigned int*)l, 16, 0, 0);
}

// ---------------- fp32 -> bf16 conversion ----------------
__global__ __launch_bounds__(256) void cvt_f32_bf16(
    const float* __restrict__ in, unsigned short* __restrict__ out, int n)
{
    int i = (blockIdx.x * 256 + threadIdx.x) * 4;
    if (i + 3 < n) {
        float4 v = *reinterpret_cast<const float4*>(in + i);
        ushort4 o;
        o.x = f2bf(v.x); o.y = f2bf(v.y); o.z = f2bf(v.z); o.w = f2bf(v.w);
        *reinterpret_cast<ushort4*>(out + i) = o;
    }
}

// ------- bf16 GEMM: C[M][N] = A[M][K] * Bt[N][K]^T (fp32 or bf16 out) -----
#define BM 128
#define BN 128
#define BKK 64

template <bool BF16OUT>
__global__ __launch_bounds__(256) void gemm_bf16_nt(
    const unsigned short* __restrict__ A, const unsigned short* __restrict__ Bt,
    void* __restrict__ Cv, int M, int N, int K)
{
    __shared__ unsigned short As[BM][BKK];
    __shared__ unsigned short Bs[BN][BKK];
    const int tid  = threadIdx.x;
    const int lane = tid & 63;
    const int wid  = tid >> 6;
    const int r = lane & 15, g = lane >> 4;
    const int wr = wid >> 1, wc = wid & 1;
    const int m0 = blockIdx.y * BM;
    const int n0 = blockIdx.x * BN;

    f32x4 acc[4][4];
    for (int i = 0; i < 4; ++i)
        for (int j = 0; j < 4; ++j)
            acc[i][j] = (f32x4){0.f, 0.f, 0.f, 0.f};

    for (int kt = 0; kt < K; kt += BKK) {
        __syncthreads();
        for (int p = 0; p < 4; ++p) {
            int idx = wid * 64 + p * 256 + lane;
            int row = idx >> 3;
            int ch  = (idx & 7) * 8;
            gload16(&A[(size_t)(m0 + row) * K + kt + ch],
                    (char*)As + (size_t)(wid * 64 + p * 256) * 16);
            gload16(&Bt[(size_t)(n0 + row) * K + kt + ch],
                    (char*)Bs + (size_t)(wid * 64 + p * 256) * 16);
        }
        __syncthreads();
        for (int k0 = 0; k0 < BKK; k0 += 32) {
            bf16x8 a[4], b[4];
            for (int i = 0; i < 4; ++i)
                a[i] = *reinterpret_cast<const bf16x8*>(&As[wr * 64 + i * 16 + r][k0 + 8 * g]);
            for (int j = 0; j < 4; ++j)
                b[j] = *reinterpret_cast<const bf16x8*>(&Bs[wc * 64 + j * 16 + r][k0 + 8 * g]);
            for (int i = 0; i < 4; ++i)
                for (int j = 0; j < 4; ++j)
                    acc[i][j] = __builtin_amdgcn_mfma_f32_16x16x32_bf16(a[i], b[j], acc[i][j], 0, 0, 0);
        }
    }
    for (int i = 0; i < 4; ++i)
        for (int j = 0; j < 4; ++j)
            for (int t = 0; t < 4; ++t) {
                int row = m0 + wr * 64 + i * 16 + 4 * g + t;
                int col = n0 + wc * 64 + j * 16 + r;
                if (BF16OUT)
                    ((unsigned short*)Cv)[(size_t)row * N + col] = f2bf(acc[i][j][t]);
                else
                    ((float*)Cv)[(size_t)row * N + col] = acc[i][j][t];
            }
}

// ---------------- RMSnorm + RoPE + scale + layout kernel ----------------
// qkv bf16 [B*L][2304] -> Qb,Kb bf16 [BH][L][64], Vt bf16 [BH][64][L]
__global__ __launch_bounds__(256) void normrope(
    const unsigned short* __restrict__ qkv, const float* __restrict__ cosb,
    const float* __restrict__ sinb, const float* __restrict__ qw,
    const float* __restrict__ kw,
    unsigned short* __restrict__ Qb, unsigned short* __restrict__ Kb,
    unsigned short* __restrict__ Vt)
{
    __shared__ unsigned short vt[64][66];
    int blk = blockIdx.x;
    int lt = blk & 63;
    int bh = blk >> 6;
    int b = bh / NHEAD, h = bh % NHEAD;
    int wid = threadIdx.x >> 6, lane = threadIdx.x & 63;
    float qwv = qw[lane], kwv = kw[lane];
    float sgn = (lane < 32) ? -1.f : 1.f;

    for (int i = 0; i < 16; ++i) {
        int ll = wid * 16 + i;
        int l = lt * 64 + ll;
        size_t rowb = ((size_t)(b * L_SEQ + l)) * (3 * DMODEL) + h * HDIM + lane;
        float qv = bf2f(qkv[rowb]);
        float kv = bf2f(qkv[rowb + DMODEL]);
        unsigned short vv = qkv[rowb + 2 * DMODEL];
        float sq = qv * qv, sk = kv * kv;
        for (int off = 32; off; off >>= 1) {
            sq += __shfl_xor(sq, off);
            sk += __shfl_xor(sk, off);
        }
        float qn = qv * rsqrtf(sq * (1.f / 64.f) + 1e-6f) * qwv;
        float kn = kv * rsqrtf(sk * (1.f / 64.f) + 1e-6f) * kwv;
        float c = cosb[l * HDIM + lane], s = sinb[l * HDIM + lane];
        float qo = __shfl_xor(qn, 32), ko = __shfl_xor(kn, 32);
        float qr = qn * c + sgn * qo * s;
        float kr = kn * c + sgn * ko * s;
        qr *= 0.125f * 1.44269504f;   // fold 1/sqrt(HD) AND log2(e) into Q (exp2 softmax)
        size_t o = ((size_t)bh * L_SEQ + l) * HDIM + lane;
        Qb[o] = f2bf(qr);
        Kb[o] = f2bf(kr);
        vt[ll][lane] = vv;
    }
    __syncthreads();
    for (int i = 0; i < 16; ++i) {
        int d = wid * 16 + i;
        Vt[((size_t)bh * HDIM + d) * L_SEQ + lt * 64 + lane] = vt[lane][d];
    }
}

// ---------------- flash attention (no-max softmax, swizzled LDS, dbuf) ----
// Scores are globally bounded: |q.k| <= ||q||*||k|| = 1*8 -> |s_log2| <= 11.6,
// so exp2(s) never overflows fp32 and max-tracking is unnecessary.
// Q,K bf16 [BH][L][64] (Q pre-scaled incl log2e), Vt bf16 [BH][64][L]
// Per block: 4 waves x 32 q-rows = 128 q. KBLK = 64. Double-buffered K/V.
__global__ __launch_bounds__(256, 3) void flashattn(
    const unsigned short* __restrict__ Qb, const unsigned short* __restrict__ Kb,
    const unsigned short* __restrict__ Vt, unsigned short* __restrict__ aob)
{
    __shared__ unsigned short Ks[2][64 * 64];   // [k=64][d=64], swizzled
    __shared__ unsigned short Vs[2][64 * 64];   // [d=64][k=64], swizzled
    __shared__ unsigned short Ps[4][32 * 64];   // per-wave [q=32][k=64], swizzled

    const int bh = blockIdx.y;
    const int b = bh / NHEAD, h = bh % NHEAD;
    const int tid = threadIdx.x;
    const int wid = tid >> 6, lane = tid & 63;
    const int r = lane & 15, g = lane >> 4;
    const int q0 = blockIdx.x * 128 + wid * 32;
    const int rsw = (r & 7) << 4;

    // Q frags: lane holds Q[q0 + i*16 + r][c*32 + 8g .. +7]
    bf16x8 qf[2][2];
    for (int i = 0; i < 2; ++i) {
        const unsigned short* Qp = Qb + ((size_t)bh * L_SEQ + q0 + i * 16 + r) * HDIM + 8 * g;
        qf[i][0] = *reinterpret_cast<const bf16x8*>(Qp);
        qf[i][1] = *reinterpret_cast<const bf16x8*>(Qp + 32);
    }

    // ones B-frag: column 0 of an extra output block = row-sum accumulator
    bf16x8 onesf;
    for (int e = 0; e < 8; ++e) onesf[e] = (r == 0) ? (short)0x3F80 : (short)0;

    const unsigned short* Kbase = Kb + (size_t)bh * L_SEQ * HDIM;
    const unsigned short* Vbase = Vt + (size_t)bh * HDIM * L_SEQ;
    char* PsB = (char*)Ps[wid];

    f32x4 o[2][4];
    for (int i = 0; i < 2; ++i)
        for (int j = 0; j < 4; ++j) o[i][j] = (f32x4){0.f, 0.f, 0.f, 0.f};
    f32x4 o_l[2];   // l accumulator: lane r==0 holds l for q=i*16+4g+t
    o_l[0] = (f32x4){0.f, 0.f, 0.f, 0.f};
    o_l[1] = (f32x4){0.f, 0.f, 0.f, 0.f};

    auto stage = [&](int buf, int kb) {
        for (int p = 0; p < 2; ++p) {
            int idx = wid * 64 + p * 256 + lane;
            int row = idx >> 3;
            int colb = ((idx & 7) * 16) ^ ((row & 7) << 4);
            gload16(Kbase + (size_t)(kb + row) * HDIM + (colb >> 1),
                    (char*)Ks[buf] + (size_t)(wid * 64 + p * 256) * 16);
            gload16(Vbase + (size_t)row * L_SEQ + kb + (colb >> 1),
                    (char*)Vs[buf] + (size_t)(wid * 64 + p * 256) * 16);
        }
    };

    stage(0, 0);
    __syncthreads();
    int cur = 0;

    for (int kb = 0; kb < L_SEQ; kb += 64) {
        if (kb + 64 < L_SEQ) stage(cur ^ 1, kb + 64);
        char* KsB = (char*)Ks[cur];
        char* VsB = (char*)Vs[cur];

        // QK^T swapped: s[i][kt] = K-tile(kt) x Q(i) -> S[q=r][k=kt*16+4g+t]
        f32x4 s[2][4];
        for (int i = 0; i < 2; ++i)
            for (int kt = 0; kt < 4; ++kt) s[i][kt] = (f32x4){0.f, 0.f, 0.f, 0.f};
        for (int kt = 0; kt < 4; ++kt) {
            bf16x8 kf0 = *reinterpret_cast<const bf16x8*>(KsB + (kt * 16 + r) * 128 + ((16 * g) ^ rsw));
            bf16x8 kf1 = *reinterpret_cast<const bf16x8*>(KsB + (kt * 16 + r) * 128 + ((64 + 16 * g) ^ rsw));
            for (int i = 0; i < 2; ++i) {
                s[i][kt] = __builtin_amdgcn_mfma_f32_16x16x32_bf16(kf0, qf[i][0], s[i][kt], 0, 0, 0);
                s[i][kt] = __builtin_amdgcn_mfma_f32_16x16x32_bf16(kf1, qf[i][1], s[i][kt], 0, 0, 0);
            }
        }

        // softmax numerator: p = exp2(s)  (no max, no sum — both via MFMA/epilogue)
        for (int i = 0; i < 2; ++i) {
            for (int kt = 0; kt < 4; ++kt) {
                float p0 = __builtin_amdgcn_exp2f(s[i][kt][0]);
                float p1 = __builtin_amdgcn_exp2f(s[i][kt][1]);
                float p2 = __builtin_amdgcn_exp2f(s[i][kt][2]);
                float p3 = __builtin_amdgcn_exp2f(s[i][kt][3]);
                uint2 w2;
                w2.x = pack2bf(p0, p1);
                w2.y = pack2bf(p2, p3);
                int dst = (i * 16 + r) * 128 + ((kt * 32 + 8 * g) ^ rsw);
                *reinterpret_cast<uint2*>(PsB + dst) = w2;
            }
        }

        // PV + row-sum: read P A-frags (per-wave LDS), V^T B-frags (shared LDS)
        bf16x8 pa[2][2];
        for (int i = 0; i < 2; ++i) {
            pa[i][0] = *reinterpret_cast<const bf16x8*>(PsB + (i * 16 + r) * 128 + ((16 * g) ^ rsw));
            pa[i][1] = *reinterpret_cast<const bf16x8*>(PsB + (i * 16 + r) * 128 + ((64 + 16 * g) ^ rsw));
        }
        for (int i = 0; i < 2; ++i) {
            o_l[i] = __builtin_amdgcn_mfma_f32_16x16x32_bf16(pa[i][0], onesf, o_l[i], 0, 0, 0);
            o_l[i] = __builtin_amdgcn_mfma_f32_16x16x32_bf16(pa[i][1], onesf, o_l[i], 0, 0, 0);
        }
        for (int j = 0; j < 4; ++j) {
            bf16x8 vf0 = *reinterpret_cast<const bf16x8*>(VsB + (j * 16 + r) * 128 + ((16 * g) ^ rsw));
            bf16x8 vf1 = *reinterpret_cast<const bf16x8*>(VsB + (j * 16 + r) * 128 + ((64 + 16 * g) ^ rsw));
            for (int i = 0; i < 2; ++i) {
                o[i][j] = __builtin_amdgcn_mfma_f32_16x16x32_bf16(pa[i][0], vf0, o[i][j], 0, 0, 0);
                o[i][j] = __builtin_amdgcn_mfma_f32_16x16x32_bf16(pa[i][1], vf1, o[i][j], 0, 0, 0);
            }
        }
        __syncthreads();
        cur ^= 1;
    }

    // epilogue: O rows q = i*16+4g+t, col d = j*16+r; l[q=4g+t] at lane 16g reg t
    for (int i = 0; i < 2; ++i) {
        float i0 = 1.f / __shfl(o_l[i][0], 16 * g);
        float i1 = 1.f / __shfl(o_l[i][1], 16 * g);
        float i2 = 1.f / __shfl(o_l[i][2], 16 * g);
        float i3 = 1.f / __shfl(o_l[i][3], 16 * g);
        for (int j = 0; j < 4; ++j) {
            size_t base = ((size_t)(b * L_SEQ + q0 + i * 16 + 4 * g)) * DMODEL + h * HDIM + j * 16 + r;
            aob[base] = f2bf(o[i][j][0] * i0);
            aob[base + DMODEL] = f2bf(o[i][j][1] * i1);
            aob[base + 2 * DMODEL] = f2bf(o[i][j][2] * i2);
            aob[base + 3 * DMODEL] = f2bf(o[i][j][3] * i3);
        }
    }
}

// ---------------- launch ----------------
extern "C" void kernel_launch(void* const* d_in, const int* in_sizes, int n_in,
                              void* d_out, int out_size, void* d_ws, size_t ws_size,
                              hipStream_t stream) {
    const float* x        = (const float*)d_in[0];
    const float* rope_cos = (const float*)d_in[1];
    const float* rope_sin = (const float*)d_in[2];
    const float* Wqkv     = (const float*)d_in[3];
    const float* Wout     = (const float*)d_in[4];
    const float* q_norm_w = (const float*)d_in[5];
    const float* k_norm_w = (const float*)d_in[6];
    float* out = (float*)d_out;

    const int BL = 2 * L_SEQ;
    const int nx    = BL * DMODEL;
    const int nwqkv = 3 * DMODEL * DMODEL;
    const int nwout = DMODEL * DMODEL;
    const int nqkv  = BL * 3 * DMODEL;

    char* w = (char*)d_ws;
    unsigned short* xb    = (unsigned short*)w; w += (size_t)nx * 2;
    unsigned short* wqkvb = (unsigned short*)w; w += (size_t)nwqkv * 2;
    unsigned short* woutb = (unsigned short*)w; w += (size_t)nwout * 2;
    unsigned short* Qb    = (unsigned short*)w; w += (size_t)nx * 2;
    unsigned short* Kb    = (unsigned short*)w; w += (size_t)nx * 2;
    unsigned short* Vtb   = (unsigned short*)w; w += (size_t)nx * 2;
    unsigned short* qkvb  = (unsigned short*)w; w += (size_t)nqkv * 2;
    unsigned short* aob = qkvb;  // reuse: qkvb dead after normrope

    cvt_f32_bf16<<<nx / 1024, 256, 0, stream>>>(x, xb, nx);
    cvt_f32_bf16<<<nwqkv / 1024, 256, 0, stream>>>(Wqkv, wqkvb, nwqkv);
    cvt_f32_bf16<<<nwout / 1024, 256, 0, stream>>>(Wout, woutb, nwout);

    {
        dim3 grid(3 * DMODEL / BN, BL / BM);
        gemm_bf16_nt<true><<<grid, 256, 0, stream>>>(xb, wqkvb, qkvb, BL, 3 * DMODEL, DMODEL);
    }

    normrope<<<24 * 64, 256, 0, stream>>>(qkvb, rope_cos, rope_sin, q_norm_w, k_norm_w,
                                          Qb, Kb, Vtb);

    {
        dim3 grid(L_SEQ / 128, 24);
        flashattn<<<grid, 256, 0, stream>>>(Qb, Kb, Vtb, aob);
    }

    {
        dim3 grid(DMODEL / BN, BL / BM);
        gemm_bf16_nt<false><<<grid, 256, 0, stream>>>(aob, woutb, out, BL, DMODEL, DMODEL);
    }
}

// Round 6
// 222.460 us; speedup vs baseline: 2.8108x; 1.0758x over previous
//
#include <hip/hip_runtime.h>
#include <hip/hip_bf16.h>

typedef float f32x4 __attribute__((ext_vector_type(4)));
typedef short bf16x8 __attribute__((ext_vector_type(8)));
typedef unsigned short ushort8_t __attribute__((ext_vector_type(8)));

#define L_SEQ 4096
#define DMODEL 768
#define NHEAD 12
#define HDIM 64
#define QSCALE (0.125f * 1.44269504f)   // 1/sqrt(64) * log2(e)

__device__ __forceinline__ unsigned short f2bf(float f) {
    __hip_bfloat16 h = __float2bfloat16(f);
    return *reinterpret_cast<unsigned short*>(&h);
}

__device__ __forceinline__ unsigned pack2bf(float a, float b) {
    return (unsigned)f2bf(a) | ((unsigned)f2bf(b) << 16);
}

__device__ __forceinline__ void gload16(const void* g, void* l) {
    __builtin_amdgcn_global_load_lds(
        (const __attribute__((address_space(1))) unsigned int*)g,
        (__attribute__((address_space(3))) unsigned int*)l, 16, 0, 0);
}

// ---------------- fp32 -> bf16 conversion ----------------
__global__ __launch_bounds__(256) void cvt_f32_bf16(
    const float* __restrict__ in, unsigned short* __restrict__ out, int n)
{
    int i = (blockIdx.x * 256 + threadIdx.x) * 4;
    if (i + 3 < n) {
        float4 v = *reinterpret_cast<const float4*>(in + i);
        ushort4 o;
        o.x = f2bf(v.x); o.y = f2bf(v.y); o.z = f2bf(v.z); o.w = f2bf(v.w);
        *reinterpret_cast<ushort4*>(out + i) = o;
    }
}

#define BM 128
#define BN 128
#define BKK 64

// ------- GEMM1 + fused RMSnorm/RoPE/scale/transpose epilogue --------------
// qkv = x[8192][768] * Wqkv[2304][768]^T, then per wave-quadrant (64 cols =
// exactly one head of q, k, or v): norm+rope+scale -> Qb/Kb, transpose -> Vt.
__global__ __launch_bounds__(256) void gemm_qkv_fused(
    const unsigned short* __restrict__ A, const unsigned short* __restrict__ Bt,
    const float* __restrict__ cosb, const float* __restrict__ sinb,
    const float* __restrict__ qw, const float* __restrict__ kw,
    unsigned short* __restrict__ Qb, unsigned short* __restrict__ Kb,
    unsigned short* __restrict__ Vt)
{
    __shared__ union SM {
        struct { unsigned short As[BM][BKK]; unsigned short Bs[BN][BKK]; } st;
        unsigned short ep[4][64][72];   // per-wave epilogue tile (16B-aligned rows)
    } sm;

    const int K = DMODEL, M_ = 2 * L_SEQ;
    const int tid  = threadIdx.x;
    const int lane = tid & 63;
    const int wid  = tid >> 6;
    const int r = lane & 15, g = lane >> 4;
    const int wr = wid >> 1, wc = wid & 1;
    const int m0 = blockIdx.y * BM;
    const int n0 = blockIdx.x * BN;
    (void)M_;

    f32x4 acc[4][4];
    for (int i = 0; i < 4; ++i)
        for (int j = 0; j < 4; ++j)
            acc[i][j] = (f32x4){0.f, 0.f, 0.f, 0.f};

    for (int kt = 0; kt < K; kt += BKK) {
        __syncthreads();
        for (int p = 0; p < 4; ++p) {
            int idx = wid * 64 + p * 256 + lane;
            int row = idx >> 3;
            int ch  = (idx & 7) * 8;
            gload16(&A[(size_t)(m0 + row) * K + kt + ch],
                    (char*)sm.st.As + (size_t)(wid * 64 + p * 256) * 16);
            gload16(&Bt[(size_t)(n0 + row) * K + kt + ch],
                    (char*)sm.st.Bs + (size_t)(wid * 64 + p * 256) * 16);
        }
        __syncthreads();
        for (int k0 = 0; k0 < BKK; k0 += 32) {
            bf16x8 a[4], b[4];
            for (int i = 0; i < 4; ++i)
                a[i] = *reinterpret_cast<const bf16x8*>(&sm.st.As[wr * 64 + i * 16 + r][k0 + 8 * g]);
            for (int j = 0; j < 4; ++j)
                b[j] = *reinterpret_cast<const bf16x8*>(&sm.st.Bs[wc * 64 + j * 16 + r][k0 + 8 * g]);
            for (int i = 0; i < 4; ++i)
                for (int j = 0; j < 4; ++j)
                    acc[i][j] = __builtin_amdgcn_mfma_f32_16x16x32_bf16(a[i], b[j], acc[i][j], 0, 0, 0);
        }
    }

    __syncthreads();   // all waves done with As/Bs; safe to reuse LDS as ep

    const int e0  = n0 + wc * 64;          // first e-col of this wave (one head)
    const int sec = e0 / DMODEL;           // 0=q, 1=k, 2=v
    const int h   = (e0 % DMODEL) / HDIM;
    const int row0 = m0 + wr * 64;         // 64 rows, never straddles batch
    const int b   = row0 >> 12;
    const int l0  = row0 & (L_SEQ - 1);
    unsigned short (*ep)[72] = sm.ep[wid];

    if (sec < 2) {
        // RMS-norm + RoPE + (Q only) scale
        const float* nw = (sec == 0) ? qw : kw;
        float wv[4];
        for (int j = 0; j < 4; ++j) wv[j] = nw[j * 16 + r];
        for (int i = 0; i < 4; ++i) {
            for (int t = 0; t < 4; ++t) {
                float ss = acc[i][0][t] * acc[i][0][t] + acc[i][1][t] * acc[i][1][t]
                         + acc[i][2][t] * acc[i][2][t] + acc[i][3][t] * acc[i][3][t];
                ss += __shfl_xor(ss, 1);
                ss += __shfl_xor(ss, 2);
                ss += __shfl_xor(ss, 4);
                ss += __shfl_xor(ss, 8);
                float inv = rsqrtf(ss * (1.f / 64.f) + 1e-6f);
                int lr = i * 16 + 4 * g + t;
                int l  = l0 + lr;
                float qn[4];
                for (int j = 0; j < 4; ++j) qn[j] = acc[i][j][t] * inv * wv[j];
                for (int j = 0; j < 4; ++j) {
                    int d = j * 16 + r;
                    float c = cosb[l * HDIM + d], s = sinb[l * HDIM + d];
                    float sgn = (j < 2) ? -1.f : 1.f;
                    float res = qn[j] * c + sgn * qn[j ^ 2] * s;
                    if (sec == 0) res *= QSCALE;
                    ep[lr][d] = f2bf(res);
                }
            }
        }
        unsigned short* dst = ((sec == 0) ? Qb : Kb)
            + ((size_t)(b * NHEAD + h) * L_SEQ + l0) * HDIM;
        for (int it = 0; it < 8; ++it) {
            int idx = it * 64 + lane;
            int lr = idx >> 3, ch = (idx & 7) * 8;
            ushort8_t v = *reinterpret_cast<const ushort8_t*>(&ep[lr][ch]);
            *reinterpret_cast<ushort8_t*>(&dst[(size_t)lr * HDIM + ch]) = v;
        }
    } else {
        // V: transpose to [BH][64 d][L]
        for (int i = 0; i < 4; ++i)
            for (int t = 0; t < 4; ++t) {
                int lr = i * 16 + 4 * g + t;
                for (int j = 0; j < 4; ++j)
                    ep[j * 16 + r][lr] = f2bf(acc[i][j][t]);
            }
        unsigned short* dst = Vt + ((size_t)(b * NHEAD + h) * HDIM) * L_SEQ + l0;
        for (int it = 0; it < 8; ++it) {
            int idx = it * 64 + lane;
            int d = idx >> 3, ch = (idx & 7) * 8;
            ushort8_t v = *reinterpret_cast<const ushort8_t*>(&ep[d][ch]);
            *reinterpret_cast<ushort8_t*>(&dst[(size_t)d * L_SEQ + ch]) = v;
        }
    }
}

// ------- bf16 GEMM: C[M][N] = A[M][K] * Bt[N][K]^T (fp32 out) -------------
__global__ __launch_bounds__(256) void gemm_bf16_nt(
    const unsigned short* __restrict__ A, const unsigned short* __restrict__ Bt,
    float* __restrict__ C, int M, int N, int K)
{
    __shared__ unsigned short As[BM][BKK];
    __shared__ unsigned short Bs[BN][BKK];
    const int tid  = threadIdx.x;
    const int lane = tid & 63;
    const int wid  = tid >> 6;
    const int r = lane & 15, g = lane >> 4;
    const int wr = wid >> 1, wc = wid & 1;
    const int m0 = blockIdx.y * BM;
    const int n0 = blockIdx.x * BN;

    f32x4 acc[4][4];
    for (int i = 0; i < 4; ++i)
        for (int j = 0; j < 4; ++j)
            acc[i][j] = (f32x4){0.f, 0.f, 0.f, 0.f};

    for (int kt = 0; kt < K; kt += BKK) {
        __syncthreads();
        for (int p = 0; p < 4; ++p) {
            int idx = wid * 64 + p * 256 + lane;
            int row = idx >> 3;
            int ch  = (idx & 7) * 8;
            gload16(&A[(size_t)(m0 + row) * K + kt + ch],
                    (char*)As + (size_t)(wid * 64 + p * 256) * 16);
            gload16(&Bt[(size_t)(n0 + row) * K + kt + ch],
                    (char*)Bs + (size_t)(wid * 64 + p * 256) * 16);
        }
        __syncthreads();
        for (int k0 = 0; k0 < BKK; k0 += 32) {
            bf16x8 a[4], b[4];
            for (int i = 0; i < 4; ++i)
                a[i] = *reinterpret_cast<const bf16x8*>(&As[wr * 64 + i * 16 + r][k0 + 8 * g]);
            for (int j = 0; j < 4; ++j)
                b[j] = *reinterpret_cast<const bf16x8*>(&Bs[wc * 64 + j * 16 + r][k0 + 8 * g]);
            for (int i = 0; i < 4; ++i)
                for (int j = 0; j < 4; ++j)
                    acc[i][j] = __builtin_amdgcn_mfma_f32_16x16x32_bf16(a[i], b[j], acc[i][j], 0, 0, 0);
        }
    }
    for (int i = 0; i < 4; ++i)
        for (int j = 0; j < 4; ++j)
            for (int t = 0; t < 4; ++t) {
                int row = m0 + wr * 64 + i * 16 + 4 * g + t;
                int col = n0 + wc * 64 + j * 16 + r;
                C[(size_t)row * N + col] = acc[i][j][t];
            }
}

// ---------------- flash attention (no-max softmax, swizzled LDS, dbuf) ----
// Scores globally bounded (|s_log2| <= 11.6) -> exp2 never overflows fp32.
__global__ __launch_bounds__(256, 3) void flashattn(
    const unsigned short* __restrict__ Qb, const unsigned short* __restrict__ Kb,
    const unsigned short* __restrict__ Vt, unsigned short* __restrict__ aob)
{
    __shared__ unsigned short Ks[2][64 * 64];
    __shared__ unsigned short Vs[2][64 * 64];
    __shared__ unsigned short Ps[4][32 * 64];

    const int bh = blockIdx.y;
    const int b = bh / NHEAD, h = bh % NHEAD;
    const int tid = threadIdx.x;
    const int wid = tid >> 6, lane = tid & 63;
    const int r = lane & 15, g = lane >> 4;
    const int q0 = blockIdx.x * 128 + wid * 32;
    const int rsw = (r & 7) << 4;

    bf16x8 qf[2][2];
    for (int i = 0; i < 2; ++i) {
        const unsigned short* Qp = Qb + ((size_t)bh * L_SEQ + q0 + i * 16 + r) * HDIM + 8 * g;
        qf[i][0] = *reinterpret_cast<const bf16x8*>(Qp);
        qf[i][1] = *reinterpret_cast<const bf16x8*>(Qp + 32);
    }

    bf16x8 onesf;
    for (int e = 0; e < 8; ++e) onesf[e] = (r == 0) ? (short)0x3F80 : (short)0;

    const unsigned short* Kbase = Kb + (size_t)bh * L_SEQ * HDIM;
    const unsigned short* Vbase = Vt + (size_t)bh * HDIM * L_SEQ;
    char* PsB = (char*)Ps[wid];

    f32x4 o[2][4];
    for (int i = 0; i < 2; ++i)
        for (int j = 0; j < 4; ++j) o[i][j] = (f32x4){0.f, 0.f, 0.f, 0.f};
    f32x4 o_l[2];
    o_l[0] = (f32x4){0.f, 0.f, 0.f, 0.f};
    o_l[1] = (f32x4){0.f, 0.f, 0.f, 0.f};

    auto stage = [&](int buf, int kb) {
        for (int p = 0; p < 2; ++p) {
            int idx = wid * 64 + p * 256 + lane;
            int row = idx >> 3;
            int colb = ((idx & 7) * 16) ^ ((row & 7) << 4);
            gload16(Kbase + (size_t)(kb + row) * HDIM + (colb >> 1),
                    (char*)Ks[buf] + (size_t)(wid * 64 + p * 256) * 16);
            gload16(Vbase + (size_t)row * L_SEQ + kb + (colb >> 1),
                    (char*)Vs[buf] + (size_t)(wid * 64 + p * 256) * 16);
        }
    };

    stage(0, 0);
    __syncthreads();
    int cur = 0;

    for (int kb = 0; kb < L_SEQ; kb += 64) {
        if (kb + 64 < L_SEQ) stage(cur ^ 1, kb + 64);
        char* KsB = (char*)Ks[cur];
        char* VsB = (char*)Vs[cur];

        f32x4 s[2][4];
        for (int i = 0; i < 2; ++i)
            for (int kt = 0; kt < 4; ++kt) s[i][kt] = (f32x4){0.f, 0.f, 0.f, 0.f};
        __builtin_amdgcn_s_setprio(1);
        for (int kt = 0; kt < 4; ++kt) {
            bf16x8 kf0 = *reinterpret_cast<const bf16x8*>(KsB + (kt * 16 + r) * 128 + ((16 * g) ^ rsw));
            bf16x8 kf1 = *reinterpret_cast<const bf16x8*>(KsB + (kt * 16 + r) * 128 + ((64 + 16 * g) ^ rsw));
            for (int i = 0; i < 2; ++i) {
                s[i][kt] = __builtin_amdgcn_mfma_f32_16x16x32_bf16(kf0, qf[i][0], s[i][kt], 0, 0, 0);
                s[i][kt] = __builtin_amdgcn_mfma_f32_16x16x32_bf16(kf1, qf[i][1], s[i][kt], 0, 0, 0);
            }
        }
        __builtin_amdgcn_s_setprio(0);

        for (int i = 0; i < 2; ++i) {
            for (int kt = 0; kt < 4; ++kt) {
                float p0 = __builtin_amdgcn_exp2f(s[i][kt][0]);
                float p1 = __builtin_amdgcn_exp2f(s[i][kt][1]);
                float p2 = __builtin_amdgcn_exp2f(s[i][kt][2]);
                float p3 = __builtin_amdgcn_exp2f(s[i][kt][3]);
                uint2 w2;
                w2.x = pack2bf(p0, p1);
                w2.y = pack2bf(p2, p3);
                int dst = (i * 16 + r) * 128 + ((kt * 32 + 8 * g) ^ rsw);
                *reinterpret_cast<uint2*>(PsB + dst) = w2;
            }
        }

        bf16x8 pa[2][2];
        for (int i = 0; i < 2; ++i) {
            pa[i][0] = *reinterpret_cast<const bf16x8*>(PsB + (i * 16 + r) * 128 + ((16 * g) ^ rsw));
            pa[i][1] = *reinterpret_cast<const bf16x8*>(PsB + (i * 16 + r) * 128 + ((64 + 16 * g) ^ rsw));
        }
        __builtin_amdgcn_s_setprio(1);
        for (int i = 0; i < 2; ++i) {
            o_l[i] = __builtin_amdgcn_mfma_f32_16x16x32_bf16(pa[i][0], onesf, o_l[i], 0, 0, 0);
            o_l[i] = __builtin_amdgcn_mfma_f32_16x16x32_bf16(pa[i][1], onesf, o_l[i], 0, 0, 0);
        }
        for (int j = 0; j < 4; ++j) {
            bf16x8 vf0 = *reinterpret_cast<const bf16x8*>(VsB + (j * 16 + r) * 128 + ((16 * g) ^ rsw));
            bf16x8 vf1 = *reinterpret_cast<const bf16x8*>(VsB + (j * 16 + r) * 128 + ((64 + 16 * g) ^ rsw));
            for (int i = 0; i < 2; ++i) {
                o[i][j] = __builtin_amdgcn_mfma_f32_16x16x32_bf16(pa[i][0], vf0, o[i][j], 0, 0, 0);
                o[i][j] = __builtin_amdgcn_mfma_f32_16x16x32_bf16(pa[i][1], vf1, o[i][j], 0, 0, 0);
            }
        }
        __builtin_amdgcn_s_setprio(0);
        __syncthreads();
        cur ^= 1;
    }

    for (int i = 0; i < 2; ++i) {
        float i0 = 1.f / __shfl(o_l[i][0], 16 * g);
        float i1 = 1.f / __shfl(o_l[i][1], 16 * g);
        float i2 = 1.f / __shfl(o_l[i][2], 16 * g);
        float i3 = 1.f / __shfl(o_l[i][3], 16 * g);
        for (int j = 0; j < 4; ++j) {
            size_t base = ((size_t)(b * L_SEQ + q0 + i * 16 + 4 * g)) * DMODEL + h * HDIM + j * 16 + r;
            aob[base] = f2bf(o[i][j][0] * i0);
            aob[base + DMODEL] = f2bf(o[i][j][1] * i1);
            aob[base + 2 * DMODEL] = f2bf(o[i][j][2] * i2);
            aob[base + 3 * DMODEL] = f2bf(o[i][j][3] * i3);
        }
    }
}

// ---------------- launch ----------------
extern "C" void kernel_launch(void* const* d_in, const int* in_sizes, int n_in,
                              void* d_out, int out_size, void* d_ws, size_t ws_size,
                              hipStream_t stream) {
    const float* x        = (const float*)d_in[0];
    const float* rope_cos = (const float*)d_in[1];
    const float* rope_sin = (const float*)d_in[2];
    const float* Wqkv     = (const float*)d_in[3];
    const float* Wout     = (const float*)d_in[4];
    const float* q_norm_w = (const float*)d_in[5];
    const float* k_norm_w = (const float*)d_in[6];
    float* out = (float*)d_out;

    const int BL = 2 * L_SEQ;
    const int nx    = BL * DMODEL;
    const int nwqkv = 3 * DMODEL * DMODEL;
    const int nwout = DMODEL * DMODEL;

    char* w = (char*)d_ws;
    unsigned short* xb    = (unsigned short*)w; w += (size_t)nx * 2;
    unsigned short* wqkvb = (unsigned short*)w; w += (size_t)nwqkv * 2;
    unsigned short* woutb = (unsigned short*)w; w += (size_t)nwout * 2;
    unsigned short* Qb    = (unsigned short*)w; w += (size_t)nx * 2;
    unsigned short* Kb    = (unsigned short*)w; w += (size_t)nx * 2;
    unsigned short* Vtb   = (unsigned short*)w; w += (size_t)nx * 2;
    unsigned short* aob   = (unsigned short*)w; w += (size_t)nx * 2;

    cvt_f32_bf16<<<nx / 1024, 256, 0, stream>>>(x, xb, nx);
    cvt_f32_bf16<<<nwqkv / 1024, 256, 0, stream>>>(Wqkv, wqkvb, nwqkv);
    cvt_f32_bf16<<<nwout / 1024, 256, 0, stream>>>(Wout, woutb, nwout);

    {
        dim3 grid(3 * DMODEL / BN, BL / BM);
        gemm_qkv_fused<<<grid, 256, 0, stream>>>(xb, wqkvb, rope_cos, rope_sin,
                                                 q_norm_w, k_norm_w, Qb, Kb, Vtb);
    }

    {
        dim3 grid(L_SEQ / 128, 24);
        flashattn<<<grid, 256, 0, stream>>>(Qb, Kb, Vtb, aob);
    }

    {
        dim3 grid(DMODEL / BN, BL / BM);
        gemm_bf16_nt<<<grid, 256, 0, stream>>>(aob, woutb, out, BL, DMODEL, DMODEL);
    }
}